// Round 1
// baseline (898.921 us; speedup 1.0000x reference)
//
#include <hip/hip_runtime.h>

#define N_NODES 50000
#define N_EDGES 1600000
#define N_CAND  131072
#define D 128

typedef __attribute__((ext_vector_type(8))) short short8;
typedef __attribute__((ext_vector_type(4))) float f32x4;

__device__ inline short f2bf(float f) {
  unsigned u = __builtin_bit_cast(unsigned, f);
  u = (u + 0x7FFFu + ((u >> 16) & 1u)) >> 16;
  return (short)u;
}

// ---------------- CSR build ----------------

__global__ void hist_kernel(const int* __restrict__ dst, int* __restrict__ deg, int n) {
  int e = blockIdx.x * blockDim.x + threadIdx.x;
  if (e < n) atomicAdd(&deg[dst[e]], 1);
}

__global__ __launch_bounds__(1024) void scan_kernel(const int* __restrict__ deg,
                                                    int* __restrict__ rowptr,
                                                    int* __restrict__ cursor, int n) {
  __shared__ int buf[1024];
  __shared__ int carry_s;
  int t = threadIdx.x;
  if (t == 0) { carry_s = 0; rowptr[0] = 0; }
  __syncthreads();
  for (int base = 0; base < n; base += 1024) {
    int i = base + t;
    int v = (i < n) ? deg[i] : 0;
    buf[t] = v;
    __syncthreads();
    for (int offd = 1; offd < 1024; offd <<= 1) {
      int add = (t >= offd) ? buf[t - offd] : 0;
      __syncthreads();
      buf[t] += add;
      __syncthreads();
    }
    int incl = buf[t];
    int carry = carry_s;
    if (i < n) {
      rowptr[i + 1] = carry + incl;
      cursor[i] = carry + incl - v;   // exclusive prefix = start of node i
    }
    int total = buf[1023];
    __syncthreads();
    if (t == 0) carry_s = carry + total;
    __syncthreads();
  }
}

__global__ void fill_kernel(const int* __restrict__ src, const int* __restrict__ dst,
                            int* __restrict__ cursor, int* __restrict__ csr, int n) {
  int e = blockIdx.x * blockDim.x + threadIdx.x;
  if (e < n) {
    int d = dst[e];
    int p = atomicAdd(&cursor[d], 1);
    csr[p] = src[e];
  }
}

// ---------------- gather: out[i] = x[i] + sum_{j in N(i)} x[j] ----------------

__global__ __launch_bounds__(256) void gather_kernel(const float* __restrict__ x,
                                                     const int* __restrict__ rowptr,
                                                     const int* __restrict__ csr,
                                                     float* __restrict__ out, int n) {
  int wv = threadIdx.x >> 6, lane = threadIdx.x & 63;
  int node = blockIdx.x * 4 + wv;
  if (node >= n) return;
  int beg = rowptr[node], end = rowptr[node + 1];
  float a0 = x[node * D + lane];
  float a1 = x[node * D + 64 + lane];
  for (int e = beg; e < end; e += 64) {
    int cnt = min(64, end - e);
    int sidx = (e + lane < end) ? csr[e + lane] : 0;
    for (int i = 0; i < cnt; ++i) {
      int s = __shfl(sidx, i, 64);
      a0 += x[s * D + lane];
      a1 += x[s * D + 64 + lane];
    }
  }
  out[node * D + lane] = a0;
  out[node * D + 64 + lane] = a1;
}

// ---------------- bf16 MFMA GEMM: Out = (relu?)(A @ W + bias), K=N=128 ----------------
// Fragment-major LDS layout: slot = ((tile*4 + kk)*64 + lane)*8 bf16, lane = (r&15)|(q<<4)

__global__ __launch_bounds__(128) void gemm128(const float* __restrict__ A,
                                               const float* __restrict__ W,
                                               const float* __restrict__ bias,
                                               float* __restrict__ Out, int M, int relu) {
  __shared__ short sA[16384];  // 32 KB
  __shared__ short sB[16384];  // 32 KB
  int t = threadIdx.x;
  int blockRow = blockIdx.x * 128;

  // stage A (rows, k-contig)
  for (int i = 0; i < 16; ++i) {
    int idx = t + i * 128;          // 0..2047
    int m = idx >> 4, j8 = idx & 15;
    int row = blockRow + m;
    short8 s;
    if (row < M) {
      const float* p = A + row * D + j8 * 8;
      float4 a0 = *(const float4*)p;
      float4 a1 = *(const float4*)(p + 4);
      s[0] = f2bf(a0.x); s[1] = f2bf(a0.y); s[2] = f2bf(a0.z); s[3] = f2bf(a0.w);
      s[4] = f2bf(a1.x); s[5] = f2bf(a1.y); s[6] = f2bf(a1.z); s[7] = f2bf(a1.w);
    } else {
      for (int j = 0; j < 8; ++j) s[j] = 0;
    }
    int kk = j8 >> 2, q = j8 & 3, mt = m >> 4, ln = (m & 15) | (q << 4);
    *(short8*)&sA[((mt * 4 + kk) * 64 + ln) * 8] = s;
  }
  // stage B = W^T (cols of W, k-contig)
  for (int i = 0; i < 16; ++i) {
    int idx = i * 128 + t;
    int n = idx & 127, k8 = idx >> 7;
    short8 s;
    for (int j = 0; j < 8; ++j) s[j] = f2bf(W[(k8 * 8 + j) * D + n]);
    int kk = k8 >> 2, q = k8 & 3, nt = n >> 4, ln = (n & 15) | (q << 4);
    *(short8*)&sB[((nt * 4 + kk) * 64 + ln) * 8] = s;
  }
  __syncthreads();

  int w = t >> 6, lane = t & 63;
  f32x4 acc[4][8] = {};
  for (int kk = 0; kk < 4; ++kk) {
    short8 a[4], b[8];
#pragma unroll
    for (int mt = 0; mt < 4; ++mt)
      a[mt] = *(short8*)&sA[(((w * 4 + mt) * 4 + kk) * 64 + lane) * 8];
#pragma unroll
    for (int nt = 0; nt < 8; ++nt)
      b[nt] = *(short8*)&sB[((nt * 4 + kk) * 64 + lane) * 8];
#pragma unroll
    for (int mt = 0; mt < 4; ++mt)
#pragma unroll
      for (int nt = 0; nt < 8; ++nt)
        acc[mt][nt] = __builtin_amdgcn_mfma_f32_16x16x32_bf16(a[mt], b[nt], acc[mt][nt], 0, 0, 0);
  }

  int colbase = lane & 15, rq = lane >> 4;
  float bv[8];
#pragma unroll
  for (int nt = 0; nt < 8; ++nt) bv[nt] = bias[nt * 16 + colbase];
#pragma unroll
  for (int mt = 0; mt < 4; ++mt) {
    int row0 = blockRow + w * 64 + mt * 16 + rq * 4;
#pragma unroll
    for (int nt = 0; nt < 8; ++nt) {
      int col = nt * 16 + colbase;
#pragma unroll
      for (int r = 0; r < 4; ++r) {
        int row = row0 + r;
        if (row < M) {
          float v = acc[mt][nt][r] + bv[nt];
          if (relu) v = fmaxf(v, 0.f);
          Out[row * D + col] = v;
        }
      }
    }
  }
}

// ---------------- target vector: tvec[j] = b1[j] + [ts,td] @ W1[0:256] ----------------

__global__ __launch_bounds__(128) void tvec_kernel(const float* __restrict__ x,
                                                   const int* __restrict__ ep,
                                                   const float* __restrict__ W1,
                                                   const float* __restrict__ b1,
                                                   float* __restrict__ tvec) {
  __shared__ float su[128], sv[128];
  int j = threadIdx.x;
  int u = ep[0], v = ep[1];
  su[j] = x[u * D + j];
  sv[j] = x[v * D + j];
  __syncthreads();
  float acc = b1[j];
  for (int k = 0; k < 128; ++k) {
    float s = su[k] + sv[k];
    float d = fabsf(su[k] - sv[k]);
    acc += s * W1[k * D + j] + d * W1[(128 + k) * D + j];
  }
  tvec[j] = acc;
}

// ---------------- predictor: scores[c] = relu(tvec + [cs,cd]@W1[256:512]) @ w2 + b2 ----------------

__global__ __launch_bounds__(128) void pred_kernel(const float* __restrict__ x,
                                                   const int* __restrict__ cand,
                                                   const float* __restrict__ W1,
                                                   const float* __restrict__ tvec,
                                                   const float* __restrict__ w2,
                                                   const float* __restrict__ b2,
                                                   float* __restrict__ out) {
  __shared__ short sA[16384];
  __shared__ short sB[16384];
  int t = threadIdx.x;
  int blockRow = blockIdx.x * 128;
  int w = t >> 6, lane = t & 63;
  f32x4 acc[4][8] = {};

  for (int p = 0; p < 2; ++p) {
    __syncthreads();
    // stage A: phase 0 = xu+xv, phase 1 = |xu-xv|
    for (int i = 0; i < 16; ++i) {
      int idx = t + i * 128;
      int m = idx >> 4, j8 = idx & 15;
      int c = blockRow + m;
      int u = cand[2 * c], v = cand[2 * c + 1];
      const float* pu = x + u * D + j8 * 8;
      const float* pv = x + v * D + j8 * 8;
      float4 u0 = *(const float4*)pu;
      float4 u1 = *(const float4*)(pu + 4);
      float4 v0 = *(const float4*)pv;
      float4 v1 = *(const float4*)(pv + 4);
      float uu[8] = {u0.x, u0.y, u0.z, u0.w, u1.x, u1.y, u1.z, u1.w};
      float vv[8] = {v0.x, v0.y, v0.z, v0.w, v1.x, v1.y, v1.z, v1.w};
      short8 s;
#pragma unroll
      for (int j = 0; j < 8; ++j) {
        float val = p ? fabsf(uu[j] - vv[j]) : (uu[j] + vv[j]);
        s[j] = f2bf(val);
      }
      int kk = j8 >> 2, q = j8 & 3, mt = m >> 4, ln = (m & 15) | (q << 4);
      *(short8*)&sA[((mt * 4 + kk) * 64 + ln) * 8] = s;
    }
    // stage B from W1 rows [256 + p*128, 256 + p*128 + 128)
    const float* Wp = W1 + (256 + p * 128) * D;
    for (int i = 0; i < 16; ++i) {
      int idx = i * 128 + t;
      int n = idx & 127, k8 = idx >> 7;
      short8 s;
      for (int j = 0; j < 8; ++j) s[j] = f2bf(Wp[(k8 * 8 + j) * D + n]);
      int kk = k8 >> 2, q = k8 & 3, nt = n >> 4, ln = (n & 15) | (q << 4);
      *(short8*)&sB[((nt * 4 + kk) * 64 + ln) * 8] = s;
    }
    __syncthreads();
    for (int kk = 0; kk < 4; ++kk) {
      short8 a[4], b[8];
#pragma unroll
      for (int mt = 0; mt < 4; ++mt)
        a[mt] = *(short8*)&sA[(((w * 4 + mt) * 4 + kk) * 64 + lane) * 8];
#pragma unroll
      for (int nt = 0; nt < 8; ++nt)
        b[nt] = *(short8*)&sB[((nt * 4 + kk) * 64 + lane) * 8];
#pragma unroll
      for (int mt = 0; mt < 4; ++mt)
#pragma unroll
        for (int nt = 0; nt < 8; ++nt)
          acc[mt][nt] = __builtin_amdgcn_mfma_f32_16x16x32_bf16(a[mt], b[nt], acc[mt][nt], 0, 0, 0);
    }
  }

  // epilogue: h = relu(acc + tvec[col]); score = sum_col h*w2[col] + b2
  int colbase = lane & 15, rq = lane >> 4;
  float tv[8], w2v[8];
#pragma unroll
  for (int nt = 0; nt < 8; ++nt) {
    tv[nt] = tvec[nt * 16 + colbase];
    w2v[nt] = w2[nt * 16 + colbase];
  }
  float b2v = b2[0];
#pragma unroll
  for (int mt = 0; mt < 4; ++mt) {
    float part[4] = {0.f, 0.f, 0.f, 0.f};
#pragma unroll
    for (int nt = 0; nt < 8; ++nt)
#pragma unroll
      for (int r = 0; r < 4; ++r) {
        float h = acc[mt][nt][r] + tv[nt];
        h = fmaxf(h, 0.f);
        part[r] += h * w2v[nt];
      }
#pragma unroll
    for (int r = 0; r < 4; ++r)
      for (int msk = 1; msk < 16; msk <<= 1)
        part[r] += __shfl_xor(part[r], msk, 64);
    if (colbase == 0) {
      int row0 = blockRow + w * 64 + mt * 16 + rq * 4;
#pragma unroll
      for (int r = 0; r < 4; ++r) out[row0 + r] = part[r] + b2v;
    }
  }
}

// ---------------- launch ----------------

extern "C" void kernel_launch(void* const* d_in, const int* in_sizes, int n_in,
                              void* d_out, int out_size, void* d_ws, size_t ws_size,
                              hipStream_t stream) {
  const float* x_in = (const float*)d_in[0];
  const int* edge_index = (const int*)d_in[1];   // [2][N_EDGES]
  const int* ep = (const int*)d_in[2];           // [1][2]
  const int* cand = (const int*)d_in[3];         // [N_CAND][2]
  const float* gw1 = (const float*)d_in[4];      // [3][128][128]
  const float* gb1 = (const float*)d_in[5];      // [3][128]
  const float* gw2 = (const float*)d_in[6];
  const float* gb2 = (const float*)d_in[7];
  const float* pw1 = (const float*)d_in[8];      // [512][128]
  const float* pb1 = (const float*)d_in[9];      // [128]
  const float* pw2 = (const float*)d_in[10];     // [128]
  const float* pb2 = (const float*)d_in[11];     // [1]
  float* out = (float*)d_out;

  char* ws = (char*)d_ws;
  size_t off = 0;
  auto alloc = [&](size_t bytes) {
    void* p = ws + off;
    off += (bytes + 255) & ~(size_t)255;
    return p;
  };
  float* bufA = (float*)alloc((size_t)N_NODES * D * 4);
  float* bufB = (float*)alloc((size_t)N_NODES * D * 4);
  float* bufC = (float*)alloc((size_t)N_NODES * D * 4);
  int* csr    = (int*)alloc((size_t)N_EDGES * 4);
  int* deg    = (int*)alloc((size_t)N_NODES * 4);
  int* rowptr = (int*)alloc((size_t)(N_NODES + 1) * 4);
  int* cursor = (int*)alloc((size_t)N_NODES * 4);
  float* tvec = (float*)alloc(D * 4);

  const int* src = edge_index;
  const int* dst = edge_index + N_EDGES;

  hipMemsetAsync(deg, 0, (size_t)N_NODES * 4, stream);
  hist_kernel<<<(N_EDGES + 255) / 256, 256, 0, stream>>>(dst, deg, N_EDGES);
  scan_kernel<<<1, 1024, 0, stream>>>(deg, rowptr, cursor, N_NODES);
  fill_kernel<<<(N_EDGES + 255) / 256, 256, 0, stream>>>(src, dst, cursor, csr, N_EDGES);

  const int gemm_grid = (N_NODES + 127) / 128;
  const float* xl = x_in;
  for (int l = 0; l < 3; ++l) {
    gather_kernel<<<(N_NODES + 3) / 4, 256, 0, stream>>>(xl, rowptr, csr, bufA, N_NODES);
    gemm128<<<gemm_grid, 128, 0, stream>>>(bufA, gw1 + l * D * D, gb1 + l * D, bufB, N_NODES, 1);
    gemm128<<<gemm_grid, 128, 0, stream>>>(bufB, gw2 + l * D * D, gb2 + l * D, bufC, N_NODES, 0);
    xl = bufC;
  }

  tvec_kernel<<<1, 128, 0, stream>>>(bufC, ep, pw1, pb1, tvec);
  pred_kernel<<<N_CAND / 128, 128, 0, stream>>>(bufC, cand, pw1, tvec, pw2, pb2, out);
}

// Round 2
// 645.300 us; speedup vs baseline: 1.3930x; 1.3930x over previous
//
#include <hip/hip_runtime.h>

#define N_NODES 50000
#define N_EDGES 1600000
#define N_CAND  131072
#define D 128
#define NB 196      // ceil(50000/256) coarse buckets (dst>>8)
#define BCAP 10240  // per-bucket capacity; E[cnt]=8192, sigma~90

typedef __attribute__((ext_vector_type(8))) short short8;
typedef __attribute__((ext_vector_type(4))) float f32x4;

__device__ inline short f2bf(float f) {
  unsigned u = __builtin_bit_cast(unsigned, f);
  u = (u + 0x7FFFu + ((u >> 16) & 1u)) >> 16;
  return (short)u;
}

// ---------------- CSR build: two-pass counting sort ----------------

__global__ __launch_bounds__(256) void build_pass1(const int* __restrict__ src,
                                                   const int* __restrict__ dst,
                                                   int* __restrict__ bucket_cnt,
                                                   int2* __restrict__ pairs) {
  __shared__ int lcnt[NB];
  __shared__ int lbase[NB];
  int t = threadIdx.x;
  int e0 = blockIdx.x * 2048;
  for (int i = t; i < NB; i += 256) lcnt[i] = 0;
  __syncthreads();
  int d[8], s[8], r[8];
#pragma unroll
  for (int i = 0; i < 8; ++i) {
    int e = e0 + i * 256 + t;
    if (e < N_EDGES) {
      d[i] = dst[e]; s[i] = src[e];
      r[i] = atomicAdd(&lcnt[d[i] >> 8], 1);   // LDS atomic: local rank
    } else d[i] = -1;
  }
  __syncthreads();
  for (int i = t; i < NB; i += 256) {
    int c = lcnt[i];
    lbase[i] = c ? atomicAdd(&bucket_cnt[i], c) : 0;  // 1 global atomic per (block,bucket)
  }
  __syncthreads();
#pragma unroll
  for (int i = 0; i < 8; ++i) {
    if (d[i] >= 0) {
      int b = d[i] >> 8;
      pairs[b * BCAP + lbase[b] + r[i]] = make_int2(d[i], s[i]);
    }
  }
}

__global__ __launch_bounds__(256) void bucket_scan(const int* __restrict__ bucket_cnt,
                                                   int* __restrict__ bucket_base) {
  __shared__ int buf[256];
  int t = threadIdx.x;
  int v = (t < NB) ? bucket_cnt[t] : 0;
  buf[t] = v;
  __syncthreads();
  for (int off = 1; off < 256; off <<= 1) {
    int add = (t >= off) ? buf[t - off] : 0;
    __syncthreads();
    buf[t] += add;
    __syncthreads();
  }
  if (t < NB) bucket_base[t] = buf[t] - v;      // exclusive prefix
  if (t == NB - 1) bucket_base[NB] = buf[t];
}

__global__ __launch_bounds__(256) void build_pass2(const int2* __restrict__ pairs,
                                                   const int* __restrict__ bucket_cnt,
                                                   const int* __restrict__ bucket_base,
                                                   int* __restrict__ rowptr,
                                                   int* __restrict__ csr) {
  __shared__ int cnt_s[256];
  __shared__ int buf[256];
  __shared__ int ssrc[BCAP];
  int t = threadIdx.x;
  int b = blockIdx.x;
  int node0 = b << 8;
  int cnt = bucket_cnt[b];
  int gbase = bucket_base[b];
  const int2* pp = pairs + b * BCAP;
  cnt_s[t] = 0;
  __syncthreads();
  for (int i = t; i < cnt; i += 256) {
    int2 p = pp[i];
    atomicAdd(&cnt_s[p.x - node0], 1);
  }
  __syncthreads();
  int v = cnt_s[t];
  buf[t] = v;
  __syncthreads();
  for (int off = 1; off < 256; off <<= 1) {
    int add = (t >= off) ? buf[t - off] : 0;
    __syncthreads();
    buf[t] += add;
    __syncthreads();
  }
  int excl = buf[t] - v;
  if (node0 + t < N_NODES) rowptr[node0 + t] = gbase + excl;
  if (b == NB - 1 && t == 0) rowptr[N_NODES] = gbase + cnt;
  cnt_s[t] = excl;   // cursors
  __syncthreads();
  for (int i = t; i < cnt; i += 256) {
    int2 p = pp[i];
    int pos = atomicAdd(&cnt_s[p.x - node0], 1);
    ssrc[pos] = p.y;
  }
  __syncthreads();
  for (int i = t; i < cnt; i += 256) csr[gbase + i] = ssrc[i];
}

// ---------------- gather: out[i] = x[i] + sum_{j in N(i)} x[j] ----------------

__global__ __launch_bounds__(256) void gather_kernel(const float* __restrict__ x,
                                                     const int* __restrict__ rowptr,
                                                     const int* __restrict__ csr,
                                                     float* __restrict__ out, int n) {
  int wv = threadIdx.x >> 6, lane = threadIdx.x & 63;
  int node = blockIdx.x * 4 + wv;
  if (node >= n) return;
  int beg = rowptr[node], end = rowptr[node + 1];
  float2 a = *(const float2*)&x[node * D + lane * 2];
  for (int e = beg; e < end; e += 64) {
    int cnt = min(64, end - e);
    int sidx = (e + lane < end) ? csr[e + lane] : 0;
    for (int i = 0; i < cnt; ++i) {
      int s = __shfl(sidx, i, 64);
      float2 xv = *(const float2*)&x[s * D + lane * 2];
      a.x += xv.x;
      a.y += xv.y;
    }
  }
  *(float2*)&out[node * D + lane * 2] = a;
}

// ---------------- weight prep: fragment-layout bf16 images ----------------
// img 0-2: gw1[l], img 3-5: gw2[l], img 6: pw1 rows 256-383, img 7: pw1 rows 384-511

__global__ __launch_bounds__(256) void wprep(const float* __restrict__ gw1,
                                             const float* __restrict__ gw2,
                                             const float* __restrict__ pw1,
                                             short* __restrict__ Wf) {
  int tid = blockIdx.x * 256 + threadIdx.x;  // 0..16383
  int img = tid >> 11, idx = tid & 2047;
  const float* W;
  if (img < 3) W = gw1 + img * 16384;
  else if (img < 6) W = gw2 + (img - 3) * 16384;
  else W = pw1 + (256 + (img - 6) * 128) * 128;
  int n = idx & 127, k8 = idx >> 7;
  short8 s;
#pragma unroll
  for (int j = 0; j < 8; ++j) s[j] = f2bf(W[(k8 * 8 + j) * 128 + n]);
  int kk = k8 >> 2, q = k8 & 3, nt = n >> 4, ln = (n & 15) | (q << 4);
  *(short8*)&Wf[img * 16384 + ((nt * 4 + kk) * 64 + ln) * 8] = s;
}

// ---------------- bf16 MFMA GEMM: Out = (relu?)(A @ W + bias), B frags from global ----------------

__global__ __launch_bounds__(128) void gemm128(const float* __restrict__ A,
                                               const short* __restrict__ Bf,
                                               const float* __restrict__ bias,
                                               float* __restrict__ Out, int M, int relu) {
  __shared__ short sA[16384];  // 16 KB
  int t = threadIdx.x;
  int blockRow = blockIdx.x * 128;

  for (int i = 0; i < 16; ++i) {
    int idx = t + i * 128;
    int m = idx >> 4, j8 = idx & 15;
    int row = blockRow + m;
    short8 s;
    if (row < M) {
      const float* p = A + row * D + j8 * 8;
      float4 a0 = *(const float4*)p;
      float4 a1 = *(const float4*)(p + 4);
      s[0] = f2bf(a0.x); s[1] = f2bf(a0.y); s[2] = f2bf(a0.z); s[3] = f2bf(a0.w);
      s[4] = f2bf(a1.x); s[5] = f2bf(a1.y); s[6] = f2bf(a1.z); s[7] = f2bf(a1.w);
    } else {
      for (int j = 0; j < 8; ++j) s[j] = 0;
    }
    int kk = j8 >> 2, q = j8 & 3, mt = m >> 4, ln = (m & 15) | (q << 4);
    *(short8*)&sA[((mt * 4 + kk) * 64 + ln) * 8] = s;
  }
  __syncthreads();

  int w = t >> 6, lane = t & 63;
  f32x4 acc[4][8] = {};
  for (int kk = 0; kk < 4; ++kk) {
    short8 a[4], b[8];
#pragma unroll
    for (int mt = 0; mt < 4; ++mt)
      a[mt] = *(short8*)&sA[(((w * 4 + mt) * 4 + kk) * 64 + lane) * 8];
#pragma unroll
    for (int nt = 0; nt < 8; ++nt)
      b[nt] = *(const short8*)&Bf[((nt * 4 + kk) * 64 + lane) * 8];
#pragma unroll
    for (int mt = 0; mt < 4; ++mt)
#pragma unroll
      for (int nt = 0; nt < 8; ++nt)
        acc[mt][nt] = __builtin_amdgcn_mfma_f32_16x16x32_bf16(a[mt], b[nt], acc[mt][nt], 0, 0, 0);
  }

  int colbase = lane & 15, rq = lane >> 4;
  float bv[8];
#pragma unroll
  for (int nt = 0; nt < 8; ++nt) bv[nt] = bias[nt * 16 + colbase];
#pragma unroll
  for (int mt = 0; mt < 4; ++mt) {
    int row0 = blockRow + w * 64 + mt * 16 + rq * 4;
#pragma unroll
    for (int nt = 0; nt < 8; ++nt) {
      int col = nt * 16 + colbase;
#pragma unroll
      for (int r = 0; r < 4; ++r) {
        int row = row0 + r;
        if (row < M) {
          float v = acc[mt][nt][r] + bv[nt];
          if (relu) v = fmaxf(v, 0.f);
          Out[row * D + col] = v;
        }
      }
    }
  }
}

// ---------------- target vector: tvec[j] = b1[j] + [ts,td] @ W1[0:256] ----------------

__global__ __launch_bounds__(128) void tvec_kernel(const float* __restrict__ x,
                                                   const int* __restrict__ ep,
                                                   const float* __restrict__ W1,
                                                   const float* __restrict__ b1,
                                                   float* __restrict__ tvec) {
  __shared__ float su[128], sv[128];
  int j = threadIdx.x;
  int u = ep[0], v = ep[1];
  su[j] = x[u * D + j];
  sv[j] = x[v * D + j];
  __syncthreads();
  float acc = b1[j];
  for (int k = 0; k < 128; ++k) {
    float s = su[k] + sv[k];
    float d = fabsf(su[k] - sv[k]);
    acc += s * W1[k * D + j] + d * W1[(128 + k) * D + j];
  }
  tvec[j] = acc;
}

// ---------------- predictor ----------------

__global__ __launch_bounds__(128) void pred_kernel(const float* __restrict__ x,
                                                   const int* __restrict__ cand,
                                                   const short* __restrict__ Wf,
                                                   const float* __restrict__ tvec,
                                                   const float* __restrict__ w2,
                                                   const float* __restrict__ b2,
                                                   float* __restrict__ out) {
  __shared__ short sA[16384];
  int t = threadIdx.x;
  int blockRow = blockIdx.x * 128;
  int w = t >> 6, lane = t & 63;
  f32x4 acc[4][8] = {};

  for (int p = 0; p < 2; ++p) {
    __syncthreads();
    for (int i = 0; i < 16; ++i) {
      int idx = t + i * 128;
      int m = idx >> 4, j8 = idx & 15;
      int c = blockRow + m;
      int u = cand[2 * c], v = cand[2 * c + 1];
      const float* pu = x + u * D + j8 * 8;
      const float* pv = x + v * D + j8 * 8;
      float4 u0 = *(const float4*)pu;
      float4 u1 = *(const float4*)(pu + 4);
      float4 v0 = *(const float4*)pv;
      float4 v1 = *(const float4*)(pv + 4);
      float uu[8] = {u0.x, u0.y, u0.z, u0.w, u1.x, u1.y, u1.z, u1.w};
      float vv[8] = {v0.x, v0.y, v0.z, v0.w, v1.x, v1.y, v1.z, v1.w};
      short8 s;
#pragma unroll
      for (int j = 0; j < 8; ++j) {
        float val = p ? fabsf(uu[j] - vv[j]) : (uu[j] + vv[j]);
        s[j] = f2bf(val);
      }
      int kk = j8 >> 2, q = j8 & 3, mt = m >> 4, ln = (m & 15) | (q << 4);
      *(short8*)&sA[((mt * 4 + kk) * 64 + ln) * 8] = s;
    }
    __syncthreads();
    const short* Bp = Wf + (6 + p) * 16384;
    for (int kk = 0; kk < 4; ++kk) {
      short8 a[4], b[8];
#pragma unroll
      for (int mt = 0; mt < 4; ++mt)
        a[mt] = *(short8*)&sA[(((w * 4 + mt) * 4 + kk) * 64 + lane) * 8];
#pragma unroll
      for (int nt = 0; nt < 8; ++nt)
        b[nt] = *(const short8*)&Bp[((nt * 4 + kk) * 64 + lane) * 8];
#pragma unroll
      for (int mt = 0; mt < 4; ++mt)
#pragma unroll
        for (int nt = 0; nt < 8; ++nt)
          acc[mt][nt] = __builtin_amdgcn_mfma_f32_16x16x32_bf16(a[mt], b[nt], acc[mt][nt], 0, 0, 0);
    }
  }

  int colbase = lane & 15, rq = lane >> 4;
  float tv[8], w2v[8];
#pragma unroll
  for (int nt = 0; nt < 8; ++nt) {
    tv[nt] = tvec[nt * 16 + colbase];
    w2v[nt] = w2[nt * 16 + colbase];
  }
  float b2v = b2[0];
#pragma unroll
  for (int mt = 0; mt < 4; ++mt) {
    float part[4] = {0.f, 0.f, 0.f, 0.f};
#pragma unroll
    for (int nt = 0; nt < 8; ++nt)
#pragma unroll
      for (int r = 0; r < 4; ++r) {
        float h = acc[mt][nt][r] + tv[nt];
        h = fmaxf(h, 0.f);
        part[r] += h * w2v[nt];
      }
#pragma unroll
    for (int r = 0; r < 4; ++r)
      for (int msk = 1; msk < 16; msk <<= 1)
        part[r] += __shfl_xor(part[r], msk, 64);
    if (colbase == 0) {
      int row0 = blockRow + w * 64 + mt * 16 + rq * 4;
#pragma unroll
      for (int r = 0; r < 4; ++r) out[row0 + r] = part[r] + b2v;
    }
  }
}

// ---------------- launch ----------------

extern "C" void kernel_launch(void* const* d_in, const int* in_sizes, int n_in,
                              void* d_out, int out_size, void* d_ws, size_t ws_size,
                              hipStream_t stream) {
  const float* x_in = (const float*)d_in[0];
  const int* edge_index = (const int*)d_in[1];
  const int* ep = (const int*)d_in[2];
  const int* cand = (const int*)d_in[3];
  const float* gw1 = (const float*)d_in[4];
  const float* gb1 = (const float*)d_in[5];
  const float* gw2 = (const float*)d_in[6];
  const float* gb2 = (const float*)d_in[7];
  const float* pw1 = (const float*)d_in[8];
  const float* pb1 = (const float*)d_in[9];
  const float* pw2 = (const float*)d_in[10];
  const float* pb2 = (const float*)d_in[11];
  float* out = (float*)d_out;

  char* ws = (char*)d_ws;
  size_t off = 0;
  auto alloc = [&](size_t bytes) {
    void* p = ws + off;
    off += (bytes + 255) & ~(size_t)255;
    return p;
  };
  float* bufA = (float*)alloc((size_t)N_NODES * D * 4);
  float* bufB = (float*)alloc((size_t)N_NODES * D * 4);  // aliased: pairs (16.1MB) before gemms
  float* bufC = (float*)alloc((size_t)N_NODES * D * 4);
  int* csr         = (int*)alloc((size_t)N_EDGES * 4);
  int* rowptr      = (int*)alloc((size_t)(N_NODES + 1) * 4);
  int* bucket_cnt  = (int*)alloc((size_t)NB * 4);
  int* bucket_base = (int*)alloc((size_t)(NB + 1) * 4);
  short* Wf        = (short*)alloc((size_t)8 * 16384 * 2);
  float* tvec      = (float*)alloc(D * 4);

  int2* pairs = (int2*)bufB;  // 196*10240*8B = 16.06MB < 25.6MB; consumed before gemm writes bufB

  const int* src = edge_index;
  const int* dst = edge_index + N_EDGES;

  hipMemsetAsync(bucket_cnt, 0, (size_t)NB * 4, stream);
  wprep<<<64, 256, 0, stream>>>(gw1, gw2, pw1, Wf);
  build_pass1<<<(N_EDGES + 2047) / 2048, 256, 0, stream>>>(src, dst, bucket_cnt, pairs);
  bucket_scan<<<1, 256, 0, stream>>>(bucket_cnt, bucket_base);
  build_pass2<<<NB, 256, 0, stream>>>(pairs, bucket_cnt, bucket_base, rowptr, csr);

  const int gemm_grid = (N_NODES + 127) / 128;
  const float* xl = x_in;
  for (int l = 0; l < 3; ++l) {
    gather_kernel<<<(N_NODES + 3) / 4, 256, 0, stream>>>(xl, rowptr, csr, bufA, N_NODES);
    gemm128<<<gemm_grid, 128, 0, stream>>>(bufA, Wf + l * 16384, gb1 + l * D, bufB, N_NODES, 1);
    gemm128<<<gemm_grid, 128, 0, stream>>>(bufB, Wf + (3 + l) * 16384, gb2 + l * D, bufC, N_NODES, 0);
    xl = bufC;
  }

  tvec_kernel<<<1, 128, 0, stream>>>(bufC, ep, pw1, pb1, tvec);
  pred_kernel<<<N_CAND / 128, 128, 0, stream>>>(bufC, cand, Wf, tvec, pw2, pb2, out);
}

// Round 3
// 401.595 us; speedup vs baseline: 2.2384x; 1.6068x over previous
//
#include <hip/hip_runtime.h>

#define N_NODES 50000
#define N_EDGES 1600000
#define N_CAND  131072
#define D 128
#define ROWS 50176   // padded row count (multiple of 256)
#define NB 196       // coarse buckets (dst>>8)
#define BCAP 10240

typedef __attribute__((ext_vector_type(8))) short short8;
typedef __attribute__((ext_vector_type(4))) float f32x4;

__device__ inline short f2bf(float f) {
  unsigned u = __builtin_bit_cast(unsigned, f);
  u = (u + 0x7FFFu + ((u >> 16) & 1u)) >> 16;
  return (short)u;
}
__device__ inline float bf_lo(unsigned u) { return __builtin_bit_cast(float, u << 16); }
__device__ inline float bf_hi(unsigned u) { return __builtin_bit_cast(float, u & 0xFFFF0000u); }
__device__ inline float bfu(unsigned short h) { return __builtin_bit_cast(float, (unsigned)h << 16); }

// ---------------- fp32 -> bf16 convert ----------------

__global__ __launch_bounds__(256) void cvt_bf(const float* __restrict__ x,
                                              unsigned short* __restrict__ y) {
  size_t base = ((size_t)blockIdx.x * 256 + threadIdx.x) * 8;
  float4 v0 = *(const float4*)&x[base];
  float4 v1 = *(const float4*)&x[base + 4];
  short8 s;
  s[0] = f2bf(v0.x); s[1] = f2bf(v0.y); s[2] = f2bf(v0.z); s[3] = f2bf(v0.w);
  s[4] = f2bf(v1.x); s[5] = f2bf(v1.y); s[6] = f2bf(v1.z); s[7] = f2bf(v1.w);
  *(short8*)&y[base] = s;
}

// ---------------- CSR build: two-pass counting sort (packed pairs) ----------------

__global__ __launch_bounds__(256) void build_pass1(const int* __restrict__ src,
                                                   const int* __restrict__ dst,
                                                   int* __restrict__ bucket_cnt,
                                                   int* __restrict__ pairs) {
  __shared__ int lcnt[NB];
  __shared__ int lbase[NB];
  int t = threadIdx.x;
  int e0 = blockIdx.x * 2048;
  for (int i = t; i < NB; i += 256) lcnt[i] = 0;
  __syncthreads();
  int d[8], s[8], r[8];
#pragma unroll
  for (int i = 0; i < 8; ++i) {
    int e = e0 + i * 256 + t;
    if (e < N_EDGES) {
      d[i] = dst[e]; s[i] = src[e];
      r[i] = atomicAdd(&lcnt[d[i] >> 8], 1);
    } else d[i] = -1;
  }
  __syncthreads();
  for (int i = t; i < NB; i += 256) {
    int c = lcnt[i];
    lbase[i] = c ? atomicAdd(&bucket_cnt[i], c) : 0;
  }
  __syncthreads();
#pragma unroll
  for (int i = 0; i < 8; ++i) {
    if (d[i] >= 0) {
      int b = d[i] >> 8;
      pairs[b * BCAP + lbase[b] + r[i]] = (s[i] << 8) | (d[i] & 255);
    }
  }
}

__global__ __launch_bounds__(256) void bucket_scan(const int* __restrict__ bucket_cnt,
                                                   int* __restrict__ bucket_base) {
  __shared__ int buf[256];
  int t = threadIdx.x;
  int v = (t < NB) ? bucket_cnt[t] : 0;
  buf[t] = v;
  __syncthreads();
  for (int off = 1; off < 256; off <<= 1) {
    int add = (t >= off) ? buf[t - off] : 0;
    __syncthreads();
    buf[t] += add;
    __syncthreads();
  }
  if (t < NB) bucket_base[t] = buf[t] - v;
  if (t == NB - 1) bucket_base[NB] = buf[t];
}

__global__ __launch_bounds__(256) void build_pass2(const int* __restrict__ pairs,
                                                   const int* __restrict__ bucket_cnt,
                                                   const int* __restrict__ bucket_base,
                                                   int* __restrict__ rowptr,
                                                   int* __restrict__ csr) {
  __shared__ int cnt_s[256];
  __shared__ int buf[256];
  __shared__ int ssrc[BCAP];
  int t = threadIdx.x;
  int b = blockIdx.x;
  int cnt = bucket_cnt[b];
  int gbase = bucket_base[b];
  const int* pp = pairs + b * BCAP;
  cnt_s[t] = 0;
  __syncthreads();
  for (int i = t; i < cnt; i += 256) atomicAdd(&cnt_s[pp[i] & 255], 1);
  __syncthreads();
  int v = cnt_s[t];
  buf[t] = v;
  __syncthreads();
  for (int off = 1; off < 256; off <<= 1) {
    int add = (t >= off) ? buf[t - off] : 0;
    __syncthreads();
    buf[t] += add;
    __syncthreads();
  }
  int excl = buf[t] - v;
  int node0 = b << 8;
  if (node0 + t < N_NODES) rowptr[node0 + t] = gbase + excl;
  if (b == NB - 1 && t == 0) rowptr[N_NODES] = gbase + cnt;
  cnt_s[t] = excl;
  __syncthreads();
  for (int i = t; i < cnt; i += 256) {
    int p = pp[i];
    int pos = atomicAdd(&cnt_s[p & 255], 1);
    ssrc[pos] = p >> 8;   // src (non-negative)
  }
  __syncthreads();
  for (int i = t; i < cnt; i += 256) csr[gbase + i] = ssrc[i];
}

// ---------------- gather (bf16): out = bf16(x[i] + sum_{j in N(i)} x[j]) ----------------

__global__ __launch_bounds__(256) void gather_bf(const unsigned short* __restrict__ x,
                                                 const int* __restrict__ rowptr,
                                                 const int* __restrict__ csr,
                                                 unsigned short* __restrict__ out, int n) {
  int wv = threadIdx.x >> 6, lane = threadIdx.x & 63;
  int node = blockIdx.x * 4 + wv;
  if (node >= n) return;
  int beg = rowptr[node], end = rowptr[node + 1];
  unsigned sv = *(const unsigned*)&x[(size_t)node * D + lane * 2];
  float a0 = bf_lo(sv), a1 = bf_hi(sv);
  for (int e = beg; e < end; e += 64) {
    int cnt = min(64, end - e);
    int sidx = (e + lane < end) ? csr[e + lane] : 0;
    int i = 0;
    for (; i + 8 <= cnt; i += 8) {
      unsigned v[8];
#pragma unroll
      for (int j = 0; j < 8; ++j) {
        int s = __shfl(sidx, i + j, 64);
        v[j] = *(const unsigned*)&x[(size_t)s * D + lane * 2];
      }
#pragma unroll
      for (int j = 0; j < 8; ++j) { a0 += bf_lo(v[j]); a1 += bf_hi(v[j]); }
    }
    for (; i < cnt; ++i) {
      int s = __shfl(sidx, i, 64);
      unsigned v = *(const unsigned*)&x[(size_t)s * D + lane * 2];
      a0 += bf_lo(v); a1 += bf_hi(v);
    }
  }
  unsigned r = (unsigned)(unsigned short)f2bf(a0) | ((unsigned)(unsigned short)f2bf(a1) << 16);
  *(unsigned*)&out[(size_t)node * D + lane * 2] = r;
}

// ---------------- weight prep: fragment-layout bf16 images ----------------

__global__ __launch_bounds__(256) void wprep(const float* __restrict__ gw1,
                                             const float* __restrict__ gw2,
                                             const float* __restrict__ pw1,
                                             short* __restrict__ Wf) {
  int tid = blockIdx.x * 256 + threadIdx.x;  // 0..16383
  int img = tid >> 11, idx = tid & 2047;
  const float* W;
  if (img < 3) W = gw1 + img * 16384;
  else if (img < 6) W = gw2 + (img - 3) * 16384;
  else W = pw1 + (256 + (img - 6) * 128) * 128;
  int n = idx & 127, k8 = idx >> 7;
  short8 s;
#pragma unroll
  for (int j = 0; j < 8; ++j) s[j] = f2bf(W[(k8 * 8 + j) * 128 + n]);
  int kk = k8 >> 2, q = k8 & 3, nt = n >> 4, ln = (n & 15) | (q << 4);
  *(short8*)&Wf[img * 16384 + ((nt * 4 + kk) * 64 + ln) * 8] = s;
}

// ---------------- GEMM (bf16 A direct-from-global fragments, no LDS) ----------------
// 256 threads = 4 waves; wave w owns rows blockRow + w*32 .. +31

__global__ __launch_bounds__(256) void gemm_bf(const unsigned short* __restrict__ A,
                                               const short* __restrict__ Bf,
                                               const float* __restrict__ bias,
                                               unsigned short* __restrict__ Out, int relu) {
  int t = threadIdx.x;
  int w = t >> 6, lane = t & 63;
  int q = lane >> 4, m = lane & 15;
  int rowBase = blockIdx.x * 128 + w * 32;
  f32x4 acc[2][8] = {};
#pragma unroll
  for (int kk = 0; kk < 4; ++kk) {
    short8 a[2], b[8];
#pragma unroll
    for (int mt = 0; mt < 2; ++mt)
      a[mt] = *(const short8*)&A[(size_t)(rowBase + mt * 16 + m) * D + kk * 32 + q * 8];
#pragma unroll
    for (int nt = 0; nt < 8; ++nt)
      b[nt] = *(const short8*)&Bf[((nt * 4 + kk) * 64 + lane) * 8];
#pragma unroll
    for (int mt = 0; mt < 2; ++mt)
#pragma unroll
      for (int nt = 0; nt < 8; ++nt)
        acc[mt][nt] = __builtin_amdgcn_mfma_f32_16x16x32_bf16(a[mt], b[nt], acc[mt][nt], 0, 0, 0);
  }
  float bv[8];
#pragma unroll
  for (int nt = 0; nt < 8; ++nt) bv[nt] = bias[nt * 16 + m];
#pragma unroll
  for (int mt = 0; mt < 2; ++mt) {
    int row0 = rowBase + mt * 16 + q * 4;
#pragma unroll
    for (int nt = 0; nt < 8; ++nt) {
      int col = nt * 16 + m;
#pragma unroll
      for (int r = 0; r < 4; ++r) {
        int row = row0 + r;
        if (row < N_NODES) {
          float vv = acc[mt][nt][r] + bv[nt];
          if (relu) vv = fmaxf(vv, 0.f);
          Out[(size_t)row * D + col] = (unsigned short)f2bf(vv);
        }
      }
    }
  }
}

// ---------------- target vector ----------------

__global__ __launch_bounds__(128) void tvec_kernel(const unsigned short* __restrict__ x,
                                                   const int* __restrict__ ep,
                                                   const float* __restrict__ W1,
                                                   const float* __restrict__ b1,
                                                   float* __restrict__ tvec) {
  __shared__ float su[128], sv[128];
  int j = threadIdx.x;
  int u = ep[0], v = ep[1];
  su[j] = bfu(x[(size_t)u * D + j]);
  sv[j] = bfu(x[(size_t)v * D + j]);
  __syncthreads();
  float acc = b1[j];
  for (int k = 0; k < 128; ++k) {
    float s = su[k] + sv[k];
    float d = fabsf(su[k] - sv[k]);
    acc += s * W1[k * D + j] + d * W1[(128 + k) * D + j];
  }
  tvec[j] = acc;
}

// ---------------- predictor (single-pass dual-phase staging) ----------------

__global__ __launch_bounds__(128) void pred_kernel(const unsigned short* __restrict__ x,
                                                   const int* __restrict__ cand,
                                                   const short* __restrict__ Wf,
                                                   const float* __restrict__ tvec,
                                                   const float* __restrict__ w2,
                                                   const float* __restrict__ b2,
                                                   float* __restrict__ out) {
  __shared__ short sS[16384];  // sum phase frags
  __shared__ short sD[16384];  // absdiff phase frags
  int t = threadIdx.x;
  int blockRow = blockIdx.x * 128;
  int w = t >> 6, lane = t & 63;

  for (int i = 0; i < 16; ++i) {
    int idx = t + i * 128;
    int m = idx >> 4, j8 = idx & 15;
    int c = blockRow + m;
    int2 uv = ((const int2*)cand)[c];
    short8 su8 = *(const short8*)&x[(size_t)uv.x * D + j8 * 8];
    short8 sv8 = *(const short8*)&x[(size_t)uv.y * D + j8 * 8];
    short8 ss, sd;
#pragma unroll
    for (int j = 0; j < 8; ++j) {
      float uf = bfu((unsigned short)su8[j]);
      float vf = bfu((unsigned short)sv8[j]);
      ss[j] = f2bf(uf + vf);
      sd[j] = f2bf(fabsf(uf - vf));
    }
    int kk = j8 >> 2, qq = j8 & 3, mt = m >> 4, ln = (m & 15) | (qq << 4);
    int slot = ((mt * 4 + kk) * 64 + ln) * 8;
    *(short8*)&sS[slot] = ss;
    *(short8*)&sD[slot] = sd;
  }
  __syncthreads();

  f32x4 acc[4][8] = {};
  const short* B0 = Wf + 6 * 16384;
  const short* B1 = Wf + 7 * 16384;
  for (int kk = 0; kk < 4; ++kk) {
    short8 a0[4], a1[4], b0[8], b1[8];
#pragma unroll
    for (int mt = 0; mt < 4; ++mt) {
      a0[mt] = *(short8*)&sS[(((w * 4 + mt) * 4 + kk) * 64 + lane) * 8];
      a1[mt] = *(short8*)&sD[(((w * 4 + mt) * 4 + kk) * 64 + lane) * 8];
    }
#pragma unroll
    for (int nt = 0; nt < 8; ++nt) {
      b0[nt] = *(const short8*)&B0[((nt * 4 + kk) * 64 + lane) * 8];
      b1[nt] = *(const short8*)&B1[((nt * 4 + kk) * 64 + lane) * 8];
    }
#pragma unroll
    for (int mt = 0; mt < 4; ++mt)
#pragma unroll
      for (int nt = 0; nt < 8; ++nt) {
        acc[mt][nt] = __builtin_amdgcn_mfma_f32_16x16x32_bf16(a0[mt], b0[nt], acc[mt][nt], 0, 0, 0);
        acc[mt][nt] = __builtin_amdgcn_mfma_f32_16x16x32_bf16(a1[mt], b1[nt], acc[mt][nt], 0, 0, 0);
      }
  }

  int colbase = lane & 15, rq = lane >> 4;
  float tv[8], w2v[8];
#pragma unroll
  for (int nt = 0; nt < 8; ++nt) {
    tv[nt] = tvec[nt * 16 + colbase];
    w2v[nt] = w2[nt * 16 + colbase];
  }
  float b2v = b2[0];
#pragma unroll
  for (int mt = 0; mt < 4; ++mt) {
    float part[4] = {0.f, 0.f, 0.f, 0.f};
#pragma unroll
    for (int nt = 0; nt < 8; ++nt)
#pragma unroll
      for (int r = 0; r < 4; ++r) {
        float h = acc[mt][nt][r] + tv[nt];
        h = fmaxf(h, 0.f);
        part[r] += h * w2v[nt];
      }
#pragma unroll
    for (int r = 0; r < 4; ++r)
      for (int msk = 1; msk < 16; msk <<= 1)
        part[r] += __shfl_xor(part[r], msk, 64);
    if (colbase == 0) {
      int row0 = blockRow + w * 64 + mt * 16 + rq * 4;
#pragma unroll
      for (int r = 0; r < 4; ++r) out[row0 + r] = part[r] + b2v;
    }
  }
}

// ---------------- launch ----------------

extern "C" void kernel_launch(void* const* d_in, const int* in_sizes, int n_in,
                              void* d_out, int out_size, void* d_ws, size_t ws_size,
                              hipStream_t stream) {
  const float* x_in = (const float*)d_in[0];
  const int* edge_index = (const int*)d_in[1];
  const int* ep = (const int*)d_in[2];
  const int* cand = (const int*)d_in[3];
  const float* gw1 = (const float*)d_in[4];
  const float* gb1 = (const float*)d_in[5];
  const float* gw2 = (const float*)d_in[6];
  const float* gb2 = (const float*)d_in[7];
  const float* pw1 = (const float*)d_in[8];
  const float* pb1 = (const float*)d_in[9];
  const float* pw2 = (const float*)d_in[10];
  const float* pb2 = (const float*)d_in[11];
  float* out = (float*)d_out;

  char* ws = (char*)d_ws;
  size_t off = 0;
  auto alloc = [&](size_t bytes) {
    void* p = ws + off;
    off += (bytes + 255) & ~(size_t)255;
    return p;
  };
  unsigned short* x_bf = (unsigned short*)alloc((size_t)ROWS * D * 2);  // x, overwritten by gemm2
  unsigned short* bufA = (unsigned short*)alloc((size_t)ROWS * D * 2);  // gather out (h)
  unsigned short* bufB = (unsigned short*)alloc((size_t)ROWS * D * 2);  // gemm1 out; aliases pairs early
  int* csr         = (int*)alloc((size_t)N_EDGES * 4);
  int* rowptr      = (int*)alloc((size_t)(N_NODES + 1) * 4);
  int* bucket_cnt  = (int*)alloc((size_t)NB * 4);
  int* bucket_base = (int*)alloc((size_t)(NB + 1) * 4);
  short* Wf        = (short*)alloc((size_t)8 * 16384 * 2);
  float* tvec      = (float*)alloc(D * 4);

  int* pairs = (int*)bufB;  // 196*10240*4B = 8.03MB <= 12.85MB; consumed before gemm1 writes bufB

  const int* src = edge_index;
  const int* dst = edge_index + N_EDGES;

  hipMemsetAsync(bucket_cnt, 0, (size_t)NB * 4, stream);
  wprep<<<64, 256, 0, stream>>>(gw1, gw2, pw1, Wf);
  cvt_bf<<<3125, 256, 0, stream>>>(x_in, x_bf);
  build_pass1<<<(N_EDGES + 2047) / 2048, 256, 0, stream>>>(src, dst, bucket_cnt, pairs);
  bucket_scan<<<1, 256, 0, stream>>>(bucket_cnt, bucket_base);
  build_pass2<<<NB, 256, 0, stream>>>(pairs, bucket_cnt, bucket_base, rowptr, csr);

  const int gemm_grid = (N_NODES + 127) / 128;
  for (int l = 0; l < 3; ++l) {
    gather_bf<<<(N_NODES + 3) / 4, 256, 0, stream>>>(x_bf, rowptr, csr, bufA, N_NODES);
    gemm_bf<<<gemm_grid, 256, 0, stream>>>(bufA, Wf + l * 16384, gb1 + l * D, bufB, 1);
    gemm_bf<<<gemm_grid, 256, 0, stream>>>(bufB, Wf + (3 + l) * 16384, gb2 + l * D, x_bf, 0);
  }

  tvec_kernel<<<1, 128, 0, stream>>>(x_bf, ep, pw1, pb1, tvec);
  pred_kernel<<<N_CAND / 128, 128, 0, stream>>>(x_bf, cand, Wf, tvec, pw2, pb2, out);
}

// Round 4
// 378.751 us; speedup vs baseline: 2.3734x; 1.0603x over previous
//
#include <hip/hip_runtime.h>

#define N_NODES 50000
#define N_EDGES 1600000
#define N_CAND  131072
#define D 128
#define ROWS 50176   // padded row count
#define NB 196       // coarse buckets (dst>>8)
#define BCAP 10240   // fixed per-bucket capacity (E=8192, sigma~90)
#define LSTR 132     // LDS row stride (bf16 elems) for h1 staging

typedef __attribute__((ext_vector_type(8))) short short8;
typedef __attribute__((ext_vector_type(4))) float f32x4;

__device__ inline short f2bf(float f) {
  unsigned u = __builtin_bit_cast(unsigned, f);
  u = (u + 0x7FFFu + ((u >> 16) & 1u)) >> 16;
  return (short)u;
}
__device__ inline float bf_lo(unsigned u) { return __builtin_bit_cast(float, u << 16); }
__device__ inline float bf_hi(unsigned u) { return __builtin_bit_cast(float, u & 0xFFFF0000u); }
__device__ inline float bfu(unsigned short h) { return __builtin_bit_cast(float, (unsigned)h << 16); }

// ---------------- prep: weight frag images + x fp32->bf16 ----------------
// blocks 0..63: wprep (8 imgs x 2048 slots); blocks 64..3188: cvt (6.4M elems)

__global__ __launch_bounds__(256) void prep_kernel(const float* __restrict__ gw1,
                                                   const float* __restrict__ gw2,
                                                   const float* __restrict__ pw1,
                                                   short* __restrict__ Wf,
                                                   const float* __restrict__ x,
                                                   unsigned short* __restrict__ y) {
  int b = blockIdx.x;
  if (b < 64) {
    int tid = b * 256 + threadIdx.x;  // 0..16383
    int img = tid >> 11, idx = tid & 2047;
    const float* W;
    if (img < 3) W = gw1 + img * 16384;
    else if (img < 6) W = gw2 + (img - 3) * 16384;
    else W = pw1 + (256 + (img - 6) * 128) * 128;
    int n = idx & 127, k8 = idx >> 7;
    short8 s;
#pragma unroll
    for (int j = 0; j < 8; ++j) s[j] = f2bf(W[(k8 * 8 + j) * 128 + n]);
    int kk = k8 >> 2, q = k8 & 3, nt = n >> 4, ln = (n & 15) | (q << 4);
    *(short8*)&Wf[img * 16384 + ((nt * 4 + kk) * 64 + ln) * 8] = s;
  } else {
    size_t base = ((size_t)(b - 64) * 256 + threadIdx.x) * 8;
    float4 v0 = *(const float4*)&x[base];
    float4 v1 = *(const float4*)&x[base + 4];
    short8 s;
    s[0] = f2bf(v0.x); s[1] = f2bf(v0.y); s[2] = f2bf(v0.z); s[3] = f2bf(v0.w);
    s[4] = f2bf(v1.x); s[5] = f2bf(v1.y); s[6] = f2bf(v1.z); s[7] = f2bf(v1.w);
    *(short8*)&y[base] = s;
  }
}

// ---------------- CSR build: counting sort, fixed bucket bases ----------------

__global__ __launch_bounds__(256) void build_pass1(const int* __restrict__ src,
                                                   const int* __restrict__ dst,
                                                   int* __restrict__ bucket_cnt,
                                                   int* __restrict__ pairs) {
  __shared__ int lcnt[NB];
  __shared__ int lbase[NB];
  int t = threadIdx.x;
  int e0 = blockIdx.x * 4096;
  for (int i = t; i < NB; i += 256) lcnt[i] = 0;
  __syncthreads();
  int d[16], s[16], r[16];
#pragma unroll
  for (int i = 0; i < 16; ++i) {
    int e = e0 + i * 256 + t;
    if (e < N_EDGES) {
      d[i] = dst[e]; s[i] = src[e];
      r[i] = atomicAdd(&lcnt[d[i] >> 8], 1);
    } else d[i] = -1;
  }
  __syncthreads();
  for (int i = t; i < NB; i += 256) {
    int c = lcnt[i];
    lbase[i] = c ? atomicAdd(&bucket_cnt[i], c) : 0;
  }
  __syncthreads();
#pragma unroll
  for (int i = 0; i < 16; ++i) {
    if (d[i] >= 0) {
      int b = d[i] >> 8;
      pairs[b * BCAP + lbase[b] + r[i]] = (s[i] << 8) | (d[i] & 255);
    }
  }
}

__global__ __launch_bounds__(256) void build_pass2(const int* __restrict__ pairs,
                                                   const int* __restrict__ bucket_cnt,
                                                   int2* __restrict__ rowBE,
                                                   int* __restrict__ csr) {
  __shared__ int cnt_s[256];
  __shared__ int buf[256];
  __shared__ int ssrc[BCAP];
  int t = threadIdx.x;
  int b = blockIdx.x;
  int cnt = bucket_cnt[b];
  int gbase = b * BCAP;
  const int* pp = pairs + gbase;
  cnt_s[t] = 0;
  __syncthreads();
  for (int i = t; i < cnt; i += 256) atomicAdd(&cnt_s[pp[i] & 255], 1);
  __syncthreads();
  int v = cnt_s[t];
  buf[t] = v;
  __syncthreads();
  for (int off = 1; off < 256; off <<= 1) {
    int add = (t >= off) ? buf[t - off] : 0;
    __syncthreads();
    buf[t] += add;
    __syncthreads();
  }
  int excl = buf[t] - v;
  int node = (b << 8) + t;
  if (node < N_NODES) rowBE[node] = make_int2(gbase + excl, gbase + excl + v);
  cnt_s[t] = excl;
  __syncthreads();
  for (int i = t; i < cnt; i += 256) {
    int p = pp[i];
    int pos = atomicAdd(&cnt_s[p & 255], 1);
    ssrc[pos] = p >> 8;
  }
  __syncthreads();
  for (int i = t; i < cnt; i += 256) csr[gbase + i] = ssrc[i];
}

// ---------------- gather (bf16): out = bf16(x[i] + sum_{j in N(i)} x[j]) ----------------
// readlane -> SGPR index -> SALU addressing; 16 loads in flight

__global__ __launch_bounds__(256) void gather_bf(const unsigned short* __restrict__ x,
                                                 const int2* __restrict__ rowBE,
                                                 const int* __restrict__ csr,
                                                 unsigned short* __restrict__ out, int n) {
  int wv = __builtin_amdgcn_readfirstlane(threadIdx.x >> 6);
  int lane = threadIdx.x & 63;
  int node = blockIdx.x * 4 + wv;
  if (node >= n) return;
  int2 be = rowBE[node];
  int beg = be.x, end = be.y;
  const char* xb = (const char*)x;
  int voff = lane * 4;
  unsigned sv = *(const unsigned*)(xb + (size_t)node * 256 + voff);
  float a0 = bf_lo(sv), a1 = bf_hi(sv);
  for (int e = beg; e < end; e += 64) {
    int cnt = min(64, end - e);
    int sidx = (e + lane < end) ? csr[e + lane] : 0;
    int i = 0;
    for (; i + 16 <= cnt; i += 16) {
      unsigned v[16];
#pragma unroll
      for (int j = 0; j < 16; ++j) {
        int s = __builtin_amdgcn_readlane(sidx, i + j);   // SGPR
        v[j] = *(const unsigned*)(xb + ((size_t)(unsigned)s << 8) + voff);
      }
#pragma unroll
      for (int j = 0; j < 16; ++j) { a0 += bf_lo(v[j]); a1 += bf_hi(v[j]); }
    }
    for (; i < cnt; ++i) {
      int s = __builtin_amdgcn_readlane(sidx, i);
      unsigned v = *(const unsigned*)(xb + ((size_t)(unsigned)s << 8) + voff);
      a0 += bf_lo(v); a1 += bf_hi(v);
    }
  }
  unsigned r = (unsigned)(unsigned short)f2bf(a0) | ((unsigned)(unsigned short)f2bf(a1) << 16);
  *(unsigned*)&out[(size_t)node * D + lane * 2] = r;
}

// ---------------- fused MLP: Out = relu(A@W1+b1)@W2 + b2 (bf16 in/out) ----------------
// wave-private h1 staging in LDS, no barriers

__global__ __launch_bounds__(256) void mlp_fused(const unsigned short* __restrict__ A,
                                                 const short* __restrict__ B1f,
                                                 const float* __restrict__ b1,
                                                 const short* __restrict__ B2f,
                                                 const float* __restrict__ b2,
                                                 unsigned short* __restrict__ Out) {
  __shared__ short hbuf[4][32 * LSTR];   // 4 waves x 8448 B
  int t = threadIdx.x;
  int w = t >> 6, lane = t & 63;
  int q = lane >> 4, m = lane & 15;
  int rowBase = blockIdx.x * 128 + w * 32;
  short* hw = hbuf[w];

  f32x4 acc[2][8] = {};
#pragma unroll
  for (int kk = 0; kk < 4; ++kk) {
    short8 a[2], b[8];
#pragma unroll
    for (int mt = 0; mt < 2; ++mt)
      a[mt] = *(const short8*)&A[(size_t)(rowBase + mt * 16 + m) * D + kk * 32 + q * 8];
#pragma unroll
    for (int nt = 0; nt < 8; ++nt)
      b[nt] = *(const short8*)&B1f[((nt * 4 + kk) * 64 + lane) * 8];
#pragma unroll
    for (int mt = 0; mt < 2; ++mt)
#pragma unroll
      for (int nt = 0; nt < 8; ++nt)
        acc[mt][nt] = __builtin_amdgcn_mfma_f32_16x16x32_bf16(a[mt], b[nt], acc[mt][nt], 0, 0, 0);
  }
  // h1 = relu(acc + b1) -> LDS (C-layout scatter, padded stride)
  {
    float bv[8];
#pragma unroll
    for (int nt = 0; nt < 8; ++nt) bv[nt] = b1[nt * 16 + m];
#pragma unroll
    for (int mt = 0; mt < 2; ++mt)
#pragma unroll
      for (int nt = 0; nt < 8; ++nt)
#pragma unroll
        for (int r = 0; r < 4; ++r) {
          int row = mt * 16 + q * 4 + r, col = nt * 16 + m;
          hw[row * LSTR + col] = f2bf(fmaxf(acc[mt][nt][r] + bv[nt], 0.f));
        }
  }
  // GEMM2 from LDS A-frags
  f32x4 acc2[2][8] = {};
#pragma unroll
  for (int kk = 0; kk < 4; ++kk) {
    short8 a[2], b[8];
#pragma unroll
    for (int mt = 0; mt < 2; ++mt)
      a[mt] = *(short8*)&hw[(mt * 16 + m) * LSTR + kk * 32 + q * 8];
#pragma unroll
    for (int nt = 0; nt < 8; ++nt)
      b[nt] = *(const short8*)&B2f[((nt * 4 + kk) * 64 + lane) * 8];
#pragma unroll
    for (int mt = 0; mt < 2; ++mt)
#pragma unroll
      for (int nt = 0; nt < 8; ++nt)
        acc2[mt][nt] = __builtin_amdgcn_mfma_f32_16x16x32_bf16(a[mt], b[nt], acc2[mt][nt], 0, 0, 0);
  }
  {
    float bv[8];
#pragma unroll
    for (int nt = 0; nt < 8; ++nt) bv[nt] = b2[nt * 16 + m];
#pragma unroll
    for (int mt = 0; mt < 2; ++mt) {
      int row0 = rowBase + mt * 16 + q * 4;
#pragma unroll
      for (int nt = 0; nt < 8; ++nt) {
        int col = nt * 16 + m;
#pragma unroll
        for (int r = 0; r < 4; ++r) {
          int row = row0 + r;
          if (row < N_NODES)
            Out[(size_t)row * D + col] = (unsigned short)f2bf(acc2[mt][nt][r] + bv[nt]);
        }
      }
    }
  }
}

// ---------------- target vector ----------------

__global__ __launch_bounds__(128) void tvec_kernel(const unsigned short* __restrict__ x,
                                                   const int* __restrict__ ep,
                                                   const float* __restrict__ W1,
                                                   const float* __restrict__ b1,
                                                   float* __restrict__ tvec) {
  __shared__ float su[128], sv[128];
  int j = threadIdx.x;
  int u = ep[0], v = ep[1];
  su[j] = bfu(x[(size_t)u * D + j]);
  sv[j] = bfu(x[(size_t)v * D + j]);
  __syncthreads();
  float acc = b1[j];
  for (int k = 0; k < 128; ++k) {
    float s = su[k] + sv[k];
    float d = fabsf(su[k] - sv[k]);
    acc += s * W1[k * D + j] + d * W1[(128 + k) * D + j];
  }
  tvec[j] = acc;
}

// ---------------- predictor ----------------

__global__ __launch_bounds__(128) void pred_kernel(const unsigned short* __restrict__ x,
                                                   const int* __restrict__ cand,
                                                   const short* __restrict__ Wf,
                                                   const float* __restrict__ tvec,
                                                   const float* __restrict__ w2,
                                                   const float* __restrict__ b2,
                                                   float* __restrict__ out) {
  __shared__ short sS[16384];
  __shared__ short sD[16384];
  int t = threadIdx.x;
  int blockRow = blockIdx.x * 128;
  int w = t >> 6, lane = t & 63;

  for (int i = 0; i < 16; ++i) {
    int idx = t + i * 128;
    int m = idx >> 4, j8 = idx & 15;
    int c = blockRow + m;
    int2 uv = ((const int2*)cand)[c];
    short8 su8 = *(const short8*)&x[(size_t)uv.x * D + j8 * 8];
    short8 sv8 = *(const short8*)&x[(size_t)uv.y * D + j8 * 8];
    short8 ss, sd;
#pragma unroll
    for (int j = 0; j < 8; ++j) {
      float uf = bfu((unsigned short)su8[j]);
      float vf = bfu((unsigned short)sv8[j]);
      ss[j] = f2bf(uf + vf);
      sd[j] = f2bf(fabsf(uf - vf));
    }
    int kk = j8 >> 2, qq = j8 & 3, mt = m >> 4, ln = (m & 15) | (qq << 4);
    int slot = ((mt * 4 + kk) * 64 + ln) * 8;
    *(short8*)&sS[slot] = ss;
    *(short8*)&sD[slot] = sd;
  }
  __syncthreads();

  f32x4 acc[4][8] = {};
  const short* B0 = Wf + 6 * 16384;
  const short* B1 = Wf + 7 * 16384;
  for (int kk = 0; kk < 4; ++kk) {
    short8 a0[4], a1[4], b0[8], b1[8];
#pragma unroll
    for (int mt = 0; mt < 4; ++mt) {
      a0[mt] = *(short8*)&sS[(((w * 4 + mt) * 4 + kk) * 64 + lane) * 8];
      a1[mt] = *(short8*)&sD[(((w * 4 + mt) * 4 + kk) * 64 + lane) * 8];
    }
#pragma unroll
    for (int nt = 0; nt < 8; ++nt) {
      b0[nt] = *(const short8*)&B0[((nt * 4 + kk) * 64 + lane) * 8];
      b1[nt] = *(const short8*)&B1[((nt * 4 + kk) * 64 + lane) * 8];
    }
#pragma unroll
    for (int mt = 0; mt < 4; ++mt)
#pragma unroll
      for (int nt = 0; nt < 8; ++nt) {
        acc[mt][nt] = __builtin_amdgcn_mfma_f32_16x16x32_bf16(a0[mt], b0[nt], acc[mt][nt], 0, 0, 0);
        acc[mt][nt] = __builtin_amdgcn_mfma_f32_16x16x32_bf16(a1[mt], b1[nt], acc[mt][nt], 0, 0, 0);
      }
  }

  int colbase = lane & 15, rq = lane >> 4;
  float tv[8], w2v[8];
#pragma unroll
  for (int nt = 0; nt < 8; ++nt) {
    tv[nt] = tvec[nt * 16 + colbase];
    w2v[nt] = w2[nt * 16 + colbase];
  }
  float b2v = b2[0];
#pragma unroll
  for (int mt = 0; mt < 4; ++mt) {
    float part[4] = {0.f, 0.f, 0.f, 0.f};
#pragma unroll
    for (int nt = 0; nt < 8; ++nt)
#pragma unroll
      for (int r = 0; r < 4; ++r) {
        float h = acc[mt][nt][r] + tv[nt];
        h = fmaxf(h, 0.f);
        part[r] += h * w2v[nt];
      }
#pragma unroll
    for (int r = 0; r < 4; ++r)
      for (int msk = 1; msk < 16; msk <<= 1)
        part[r] += __shfl_xor(part[r], msk, 64);
    if (colbase == 0) {
      int row0 = blockRow + w * 64 + mt * 16 + rq * 4;
#pragma unroll
      for (int r = 0; r < 4; ++r) out[row0 + r] = part[r] + b2v;
    }
  }
}

// ---------------- launch ----------------

extern "C" void kernel_launch(void* const* d_in, const int* in_sizes, int n_in,
                              void* d_out, int out_size, void* d_ws, size_t ws_size,
                              hipStream_t stream) {
  const float* x_in = (const float*)d_in[0];
  const int* edge_index = (const int*)d_in[1];
  const int* ep = (const int*)d_in[2];
  const int* cand = (const int*)d_in[3];
  const float* gw1 = (const float*)d_in[4];
  const float* gb1 = (const float*)d_in[5];
  const float* gw2 = (const float*)d_in[6];
  const float* gb2 = (const float*)d_in[7];
  const float* pw1 = (const float*)d_in[8];
  const float* pb1 = (const float*)d_in[9];
  const float* pw2 = (const float*)d_in[10];
  const float* pb2 = (const float*)d_in[11];
  float* out = (float*)d_out;

  char* ws = (char*)d_ws;
  size_t off = 0;
  auto alloc = [&](size_t bytes) {
    void* p = ws + off;
    off += (bytes + 255) & ~(size_t)255;
    return p;
  };
  unsigned short* x_bf = (unsigned short*)alloc((size_t)ROWS * D * 2);
  unsigned short* bufA = (unsigned short*)alloc((size_t)ROWS * D * 2);
  int* pairs       = (int*)alloc((size_t)NB * BCAP * 4);
  int* csr         = (int*)alloc((size_t)NB * BCAP * 4);
  int2* rowBE      = (int2*)alloc((size_t)N_NODES * 8);
  int* bucket_cnt  = (int*)alloc((size_t)NB * 4);
  short* Wf        = (short*)alloc((size_t)8 * 16384 * 2);
  float* tvec      = (float*)alloc(D * 4);

  const int* src = edge_index;
  const int* dst = edge_index + N_EDGES;

  hipMemsetAsync(bucket_cnt, 0, (size_t)NB * 4, stream);
  prep_kernel<<<3189, 256, 0, stream>>>(gw1, gw2, pw1, Wf, x_in, x_bf);
  build_pass1<<<(N_EDGES + 4095) / 4096, 256, 0, stream>>>(src, dst, bucket_cnt, pairs);
  build_pass2<<<NB, 256, 0, stream>>>(pairs, bucket_cnt, rowBE, csr);

  const int gemm_grid = (N_NODES + 127) / 128;
  for (int l = 0; l < 3; ++l) {
    gather_bf<<<(N_NODES + 3) / 4, 256, 0, stream>>>(x_bf, rowBE, csr, bufA, N_NODES);
    mlp_fused<<<gemm_grid, 256, 0, stream>>>(bufA, Wf + l * 16384, gb1 + l * D,
                                             Wf + (3 + l) * 16384, gb2 + l * D, x_bf);
  }

  tvec_kernel<<<1, 128, 0, stream>>>(x_bf, ep, pw1, pb1, tvec);
  pred_kernel<<<N_CAND / 128, 128, 0, stream>>>(x_bf, cand, Wf, tvec, pw2, pb2, out);
}